// Round 10
// baseline (271.169 us; speedup 1.0000x reference)
//
#include <hip/hip_runtime.h>
#include <hip/hip_fp16.h>
#include <stdint.h>

// Problem constants
#define B_ 32
#define T_ 2048
#define D_ 512
#define U_ 512
#define M_ (B_ * T_)
#define MAXC 4
#define BK 32

typedef _Float16 half8   __attribute__((ext_vector_type(8)));
typedef float   floatx4  __attribute__((ext_vector_type(4)));

__device__ __forceinline__ float tanh_fast(float x) {
    float ax = fabsf(x);
    float e  = __expf(2.0f * ax);
    float t  = 1.0f - 2.0f / (e + 1.0f);
    return copysignf(t, x);
}

// async global->LDS, 16B/lane; dest = wave-uniform base + lane*16
__device__ __forceinline__ void gld_lds16(const void* gsrc, void* lds_dst) {
    typedef __attribute__((address_space(1))) const char gch;
    typedef __attribute__((address_space(3))) char lch;
    __builtin_amdgcn_global_load_lds((const gch*)(uintptr_t)gsrc,
                                     (lch*)(uint32_t)(uintptr_t)lds_dst,
                                     16, 0, 0);
}

// ---------------- k_prep: {W1 -> W1T fp16 transpose} + {w2q = query @ W2} ----
__global__ __launch_bounds__(256)
void k_prep(const float* __restrict__ W1, const float* __restrict__ query,
            const float* __restrict__ W2, _Float16* __restrict__ W1T,
            float* __restrict__ w2q) {
    const int bid = blockIdx.x;
    const int tid = threadIdx.x;
    if (bid < 64) {
        __shared__ float tile[64][65];
        const int bx = bid & 7, by = bid >> 3;
        const int k0 = bx * 64, n0 = by * 64;
        const int tx = tid & 63, ty = tid >> 6;
#pragma unroll
        for (int i = 0; i < 16; ++i) {
            int r = ty * 16 + i;
            tile[r][tx] = W1[(size_t)(k0 + r) * U_ + n0 + tx];
        }
        __syncthreads();
#pragma unroll
        for (int i = 0; i < 16; ++i) {
            int r = ty * 16 + i;
            W1T[(size_t)(n0 + r) * D_ + k0 + tx] = (_Float16)tile[tx][r];
        }
    } else {
        __shared__ float sq[D_];
        __shared__ float part[128];
        const int id = bid - 64;
        const int b  = id >> 2;
        const int nq = id & 3;
        sq[tid]       = query[b * D_ + tid];
        sq[tid + 256] = query[b * D_ + tid + 256];
        __syncthreads();
        const int n  = nq * 128 + (tid & 127);
        const int dh = tid >> 7;
        float acc = 0.f;
        const int d0 = dh * 256;
#pragma unroll 16
        for (int d = d0; d < d0 + 256; ++d)
            acc = fmaf(sq[d], W2[(size_t)d * U_ + n], acc);
        if (dh == 1) part[tid & 127] = acc;
        __syncthreads();
        if (dh == 0) w2q[b * U_ + n] = acc + part[tid];
    }
}

// ---------------- k_gemm_u: BM=128 x BN=512 x BK=32, 1024 thr, dbuf, 1 barrier/iter
// ALL LDS accesses lane-contiguous 16B (r6-law: contiguity = 0 conflicts).
// sA fp16 unit = mi*64 + lane (staged via regs by waves 0..7, cvt once);
// sB fp16 unit = inst*64 + lane (DMA'd; reads = inst*1024 + lane*16).
__global__ __launch_bounds__(1024, 4)
void k_gemm_u(const float* __restrict__ value,
              const _Float16* __restrict__ W1T,  // [N=512][K=512] fp16
              const float* __restrict__ w2q,     // [32][512]
              const float* __restrict__ Vv,      // [512]
              float* __restrict__ u_out) {       // [65536]
    __shared__ __align__(16) _Float16 sA[2][512 * 8];    // 2 x  8,192 B
    __shared__ __align__(16) _Float16 sB[2][2048 * 8];   // 2 x 32,768 B
    __shared__ float sRed[16][64];                       // 4,096 B  (total 84 KB)

    const int tid  = threadIdx.x;
    const int wv   = tid >> 6;           // 0..15
    const int l    = tid & 63;
    const int l15  = l & 15;
    const int lg   = l >> 4;             // 0..3
    const int m0   = blockIdx.x * 128;
    const int b    = m0 >> 11;
    const int wr   = (wv >> 3) * 64;     // wave row offset (0/64)
    const int wc   = (wv & 7) * 64;      // wave col offset

    // ---- A staging (threads 0..511 = waves 0..7): unit t = mis*64+lgs*16+l15s
    // holds value[row = mis*16+l15s][k0 + lgs*8 .. +8) as 8 halves.
    const int mis  = tid >> 6;           // valid when tid<512 (0..7)
    const int lgs  = (tid >> 4) & 3;
    const int l15s = tid & 15;
    const float* a_src = value + (size_t)(m0 + mis * 16 + l15s) * D_ + lgs * 8;
    const bool a_thread = (tid < 512);

    // B-DMA: wave wv issues insts wv*2+j (j=0,1); lane l fetches
    // W1T[n = inst*16 + (l&15)][k0 + (l>>4)*8 ..+8) -> unit inst*64 + l.
    const int b_n0 = l15;
    const int b_k8 = lg * 8;

#define B_ISSUE(c, buf)                                                        \
    {                                                                          \
        _Pragma("unroll")                                                      \
        for (int j = 0; j < 2; ++j) {                                          \
            const int inst = wv * 2 + j;                                       \
            const int n = inst * 16 + b_n0;                                    \
            gld_lds16(W1T + (size_t)n * D_ + (c) * BK + b_k8,                  \
                      (void*)(&sB[buf][inst * 512]));                          \
        }                                                                      \
    }

    // ---- prologue: stage A(0)+B(0) into buf 0
    B_ISSUE(0, 0);
    floatx4 ra0, ra1;
    if (a_thread) {
        ra0 = *(const floatx4*)(a_src);
        ra1 = *(const floatx4*)(a_src + 4);
        half8 h;
#pragma unroll
        for (int q = 0; q < 4; ++q) {
            h[q]     = (_Float16)ra0[q];
            h[4 + q] = (_Float16)ra1[q];
        }
        *(half8*)(&sA[0][tid * 8]) = h;
    }

    floatx4 acc[4][4];
    const floatx4 zero4 = {0.f, 0.f, 0.f, 0.f};
#pragma unroll
    for (int i = 0; i < 4; ++i)
#pragma unroll
        for (int j = 0; j < 4; ++j) acc[i][j] = zero4;

    __syncthreads();

    for (int c = 0; c < 16; ++c) {
        const int cur = c & 1;
        if (c < 15) {                      // issue next chunk's loads early
            if (a_thread) {
                ra0 = *(const floatx4*)(a_src + (c + 1) * BK);
                ra1 = *(const floatx4*)(a_src + (c + 1) * BK + 4);
            }
            B_ISSUE(c + 1, cur ^ 1);
        }

        // frags: af = sA unit mi*64+lane (contiguous); bf = sB unit inst*64+lane
        half8 af[4], bf[4];
#pragma unroll
        for (int mi = 0; mi < 4; ++mi) {
            const int mu = (wr >> 4) + mi;             // 0..7
            af[mi] = *(const half8*)(&sA[cur][(mu * 64 + l) * 8]);
        }
#pragma unroll
        for (int ni = 0; ni < 4; ++ni) {
            const int inst = (wv & 7) * 4 + ni;        // 0..31
            bf[ni] = *(const half8*)(&sB[cur][(inst * 64 + l) * 8]);
        }
#pragma unroll
        for (int ni = 0; ni < 4; ++ni)
#pragma unroll
            for (int mi = 0; mi < 4; ++mi)
                acc[mi][ni] = __builtin_amdgcn_mfma_f32_16x16x32_f16(
                    af[mi], bf[ni], acc[mi][ni], 0, 0, 0);

        if (c < 15 && a_thread) {          // cvt + write A(c+1) into other buf
            half8 h;
#pragma unroll
            for (int q = 0; q < 4; ++q) {
                h[q]     = (_Float16)ra0[q];
                h[4 + q] = (_Float16)ra1[q];
            }
            *(half8*)(&sA[cur ^ 1][tid * 8]) = h;
        }
        __syncthreads();   // drains B-DMA(c+1) + A writes; frees buf cur
    }
#undef B_ISSUE

    // ---- epilogue: ps = vv*tanh(acc + w2), reduce over 16 col-lanes (validated r9)
    float ps[4][4];
#pragma unroll
    for (int mi = 0; mi < 4; ++mi)
#pragma unroll
        for (int j = 0; j < 4; ++j) ps[mi][j] = 0.f;
#pragma unroll
    for (int ni = 0; ni < 4; ++ni) {
        const int n = wc + ni * 16 + l15;    // C/D col = lane&15
        const float w2 = w2q[b * U_ + n];
        const float vv = Vv[n];
#pragma unroll
        for (int mi = 0; mi < 4; ++mi)
#pragma unroll
            for (int j = 0; j < 4; ++j)
                ps[mi][j] += vv * tanh_fast(acc[mi][ni][j] + w2);
    }
#pragma unroll
    for (int off = 1; off < 16; off <<= 1)
#pragma unroll
        for (int mi = 0; mi < 4; ++mi)
#pragma unroll
            for (int j = 0; j < 4; ++j)
                ps[mi][j] += __shfl_xor(ps[mi][j], off, 64);

    if (l15 == 0) {
#pragma unroll
        for (int mi = 0; mi < 4; ++mi)
#pragma unroll
            for (int j = 0; j < 4; ++j)
                sRed[wv][mi * 16 + lg * 4 + j] = ps[mi][j];  // row=lg*4+j (validated)
    }
    __syncthreads();
    if (tid < 128) {
        const int half = tid >> 6, lr = tid & 63;
        float s = 0.f;
#pragma unroll
        for (int cw = 0; cw < 8; ++cw) s += sRed[half * 8 + cw][lr];
        u_out[m0 + tid] = s;
    }
}

// ---------------- k_post: top-4 select + softmax + zero cand_score ----------------
__global__ __launch_bounds__(256)
void k_post(const float* __restrict__ u, const int* __restrict__ mask,
            float* __restrict__ a_out, int* __restrict__ cand_t,
            float* __restrict__ cand_score) {
    __shared__ float sx[T_];
    __shared__ float rv[4];
    __shared__ int   ri[4];
    __shared__ float s_scalar;

    const int b = blockIdx.x;
    const int tid = threadIdx.x;
    const int wave = tid >> 6, lane = tid & 63;

    if (tid < MAXC) cand_score[b * MAXC + tid] = 0.f;

#pragma unroll
    for (int i = 0; i < 8; ++i) {
        const int t = tid * 8 + i;
        float x = u[b * T_ + t];
        if (mask[b * T_ + t] == 0) x = -1e20f;
        sx[t] = x;
    }
    __syncthreads();

    for (int r = 0; r < MAXC; ++r) {
        float v = -INFINITY; int vi = 0;
#pragma unroll
        for (int i = 0; i < 8; ++i) {
            const int t = tid * 8 + i;
            const float x = sx[t];
            if (x > v) { v = x; vi = t; }
        }
        for (int off = 32; off > 0; off >>= 1) {
            const float ov = __shfl_down(v, off, 64);
            const int   oi = __shfl_down(vi, off, 64);
            if (ov > v || (ov == v && oi < vi)) { v = ov; vi = oi; }
        }
        if (lane == 0) { rv[wave] = v; ri[wave] = vi; }
        __syncthreads();
        if (tid == 0) {
            float bv = rv[0]; int bi = ri[0];
            for (int w = 1; w < 4; ++w)
                if (rv[w] > bv || (rv[w] == bv && ri[w] < bi)) { bv = rv[w]; bi = ri[w]; }
            cand_t[b * MAXC + r] = bi;
            if (r == 0) s_scalar = bv;
            sx[bi] = -INFINITY;
        }
        __syncthreads();
    }
    const float mx = s_scalar;

    float zloc = 0.f;
    float evals[8];
#pragma unroll
    for (int i = 0; i < 8; ++i) {
        const int t = tid * 8 + i;
        float x = u[b * T_ + t];
        if (mask[b * T_ + t] == 0) x = -1e20f;
        const float e = __expf(x - mx);
        evals[i] = e;
        zloc += e;
    }
    for (int off = 32; off > 0; off >>= 1) zloc += __shfl_down(zloc, off, 64);
    if (lane == 0) rv[wave] = zloc;
    __syncthreads();
    if (tid == 0) s_scalar = 1.0f / (rv[0] + rv[1] + rv[2] + rv[3]);
    __syncthreads();
    const float rz = s_scalar;
#pragma unroll
    for (int i = 0; i < 8; ++i) {
        const int t = tid * 8 + i;
        a_out[b * T_ + t] = evals[i] * rz;
    }
}

// ---------------- k_resc: exact fp32 rescore, 256 blocks (32 b x 8 n-chunks) ----
__global__ __launch_bounds__(256)
void k_resc(const float* __restrict__ value, const float* __restrict__ W1,
            const float* __restrict__ w2q, const float* __restrict__ Vv,
            const int* __restrict__ cand_t, float* __restrict__ cand_score) {
    __shared__ __align__(16) float vrows[MAXC][D_];
    __shared__ float part[4][MAXC][64];
    const int b  = blockIdx.x >> 3;
    const int nc = blockIdx.x & 7;
    const int tid = threadIdx.x;

#pragma unroll
    for (int ci = 0; ci < MAXC; ++ci) {
        const int t = cand_t[b * MAXC + ci];
        vrows[ci][tid]       = value[((size_t)b * T_ + t) * D_ + tid];
        vrows[ci][tid + 256] = value[((size_t)b * T_ + t) * D_ + tid + 256];
    }
    __syncthreads();

    const int q  = tid >> 6;          // d-quarter (== wave)
    const int nl = tid & 63;
    const int n  = nc * 64 + nl;
    float dq[MAXC] = {0.f, 0.f, 0.f, 0.f};
    const int d0 = q * 128;
#pragma unroll 8
    for (int d = d0; d < d0 + 128; ++d) {
        const float w = W1[(size_t)d * U_ + n];
#pragma unroll
        for (int ci = 0; ci < MAXC; ++ci)
            dq[ci] = fmaf(vrows[ci][d], w, dq[ci]);
    }
#pragma unroll
    for (int ci = 0; ci < MAXC; ++ci) part[q][ci][nl] = dq[ci];
    __syncthreads();

    if (q == 0) {
        const float w2 = w2q[b * U_ + n];
        const float vv = Vv[n];
        float sc[MAXC];
#pragma unroll
        for (int ci = 0; ci < MAXC; ++ci) {
            const float dot = part[0][ci][nl] + part[1][ci][nl]
                            + part[2][ci][nl] + part[3][ci][nl];
            sc[ci] = vv * tanhf(dot + w2);
        }
#pragma unroll
        for (int off = 1; off < 64; off <<= 1)
#pragma unroll
            for (int ci = 0; ci < MAXC; ++ci)
                sc[ci] += __shfl_xor(sc[ci], off, 64);
        if (nl == 0) {
#pragma unroll
            for (int ci = 0; ci < MAXC; ++ci)
                atomicAdd(&cand_score[b * MAXC + ci], sc[ci]);
        }
    }
}

// ---------------- k_fin: exact argmax among candidates + context gather ----------
__global__ __launch_bounds__(256)
void k_fin(const float* __restrict__ value, const int* __restrict__ mask,
           const int* __restrict__ cand_t, const float* __restrict__ cand_score,
           float* __restrict__ ctx_out) {
    __shared__ int s_t;
    const int b = blockIdx.x;
    const int tid = threadIdx.x;
    if (tid == 0) {
        float bv = -INFINITY; int bt = cand_t[b * MAXC];
        for (int i = 0; i < MAXC; ++i) {
            const int   t = cand_t[b * MAXC + i];
            float s = cand_score[b * MAXC + i];
            if (mask[b * T_ + t] == 0) s = -1e20f;
            if (s > bv || (s == bv && t < bt)) { bv = s; bt = t; }
        }
        s_t = bt;
    }
    __syncthreads();
    const int t = s_t;
    ctx_out[b * D_ + tid]       = value[((size_t)b * T_ + t) * D_ + tid];
    ctx_out[b * D_ + tid + 256] = value[((size_t)b * T_ + t) * D_ + tid + 256];
}

extern "C" void kernel_launch(void* const* d_in, const int* in_sizes, int n_in,
                              void* d_out, int out_size, void* d_ws, size_t ws_size,
                              hipStream_t stream) {
    const float* value = (const float*)d_in[0];   // [32,2048,512]
    const float* query = (const float*)d_in[1];   // [32,512]
    const int*   mask  = (const int*)d_in[2];     // [32,2048]
    const float* W1    = (const float*)d_in[3];   // [512,512]
    const float* W2    = (const float*)d_in[4];   // [512,512]
    const float* Vv    = (const float*)d_in[5];   // [512]

    char* ws = (char*)d_ws;
    _Float16* W1T        = (_Float16*)ws;              // 524,288 B
    float*    w2q        = (float*)(ws + 524288);      //  65,536 B
    float*    u_ws       = (float*)(ws + 589824);      // 262,144 B
    int*      cand_t     = (int*)(ws + 851968);        //     512 B
    float*    cand_score = (float*)(ws + 852480);      //     512 B

    float* ctx_out = (float*)d_out;              // [32,512]
    float* a_out   = (float*)d_out + B_ * D_;    // [32,2048]

    hipLaunchKernelGGL(k_prep,   dim3(192), dim3(256), 0, stream,
                       W1, query, W2, W1T, w2q);
    hipLaunchKernelGGL(k_gemm_u, dim3(M_ / 128), dim3(1024), 0, stream,
                       value, W1T, w2q, Vv, u_ws);
    hipLaunchKernelGGL(k_post,   dim3(32), dim3(256), 0, stream,
                       u_ws, mask, a_out, cand_t, cand_score);
    hipLaunchKernelGGL(k_resc,   dim3(256), dim3(256), 0, stream,
                       value, W1, w2q, Vv, cand_t, cand_score);
    hipLaunchKernelGGL(k_fin,    dim3(32), dim3(256), 0, stream,
                       value, mask, cand_t, cand_score, ctx_out);
}